// Round 5
// baseline (495.312 us; speedup 1.0000x reference)
//
#include <hip/hip_runtime.h>
#include <stdint.h>

#define DEV __device__ __forceinline__

using f32x4 = __attribute__((ext_vector_type(4))) float;
using s16x8 = __attribute__((ext_vector_type(8))) short;

DEV uint16_t f2bf(float f) {
  union { float f; uint32_t u; } v; v.f = f;
  uint32_t r = v.u + 0x7fffu + ((v.u >> 16) & 1u);  // round-to-nearest-even
  return (uint16_t)(r >> 16);
}
DEV uint32_t pack2(float a, float b) {
  return (uint32_t)f2bf(a) | ((uint32_t)f2bf(b) << 16);
}

// async global->LDS, 16B per lane; LDS dest = wave-uniform base + lane*16
DEV void gload_lds16(const void* g, void* l) {
  __builtin_amdgcn_global_load_lds(
      (__attribute__((address_space(1))) void*)(void*)g,
      (__attribute__((address_space(3))) void*)l, 16, 0, 0);
}

// ---------------------------------------------------------------------------
// f32 -> bf16 conversion for q/k/v inputs (3 x 16M elems) AND the 4 weight
// matrices (4 x 1M elems), one launch. 32B read / 16B write per thread.
// ---------------------------------------------------------------------------
__global__ __launch_bounds__(256) void cvt_all_kernel(
    const float* __restrict__ q, const float* __restrict__ k,
    const float* __restrict__ v, const float* __restrict__ Wq,
    const float* __restrict__ Wk, const float* __restrict__ Wv,
    const float* __restrict__ Wp, uint16_t* __restrict__ qc,
    uint16_t* __restrict__ kc, uint16_t* __restrict__ vc,
    uint16_t* __restrict__ wqb, uint16_t* __restrict__ wkb,
    uint16_t* __restrict__ wvb, uint16_t* __restrict__ wpb) {
  const int idx = blockIdx.x * blockDim.x + threadIdx.x;
  const float* src;
  uint16_t* dst;
  int i;
  if (idx < 3 * 2097152) {  // inputs: 16M f32 each -> 2M threads each
    const int t = idx >> 21;
    i = idx & 2097151;
    src = t == 0 ? q : t == 1 ? k : v;
    dst = t == 0 ? qc : t == 1 ? kc : vc;
  } else {  // weights: 1M f32 each -> 128K threads each
    const int j = idx - 3 * 2097152;
    const int r = j >> 17;
    i = j & 131071;
    src = r == 0 ? Wq : r == 1 ? Wk : r == 2 ? Wv : Wp;
    dst = r == 0 ? wqb : r == 1 ? wkb : r == 2 ? wvb : wpb;
  }
  const float4* s = (const float4*)src;
  float4 a = s[2 * i];
  float4 b = s[2 * i + 1];
  uint4 pk;
  pk.x = pack2(a.x, a.y);
  pk.y = pack2(a.z, a.w);
  pk.z = pack2(b.x, b.y);
  pk.w = pack2(b.z, b.w);
  ((uint4*)dst)[i] = pk;
}

// ---------------------------------------------------------------------------
// NT GEMM, R5: DS-pipe offload. R4's counters showed MfmaUtil pinned at 33%
// with LDS reads at ~91% of MFMA time (A read 4x + B read 2x redundantly
// from LDS = 192KB/tile/CU @85B/cy ~= 2259cy vs MFMA 2484cy). Change: B
// (the 2MB L2-resident weight panel) is now loaded DIRECTLY global->reg
// (8 x dwordx4 per wave per K-tile, compiler register-dep-waited, no
// barrier choreography). LDS stages A only -> DS traffic 128KB/tile (~70%),
// balanced 4 ds_read_b128 per phase.
//
// Structure: 256x256 tile, BK=64, 8 waves (2Mx4N), per-wave 128x64.
// A in a 3-deep circular LDS buffer (3 x 32KB = 96KB). Per K-tile t:
//   pre-p0: load B-frags(t) to regs (stay live whole tile)
//   p0: LDA2(0) + stage A(t+2) half0 ; OPEN ; MMA2(0) ; CLOSE
//   p1: LDA2(1) + stage A(t+2) half1 ; OPEN ; MMA2(1) ; CLOSE
//   p2: LDA2(2)                      ; OPEN ; MMA2(2) ; CLOSE
//   p3: LDA2(3)                      ; OPEN ; MMA2(3) ; vmcnt ; CLOSE
// where LDA2(q) = 4 ds_read_b128 (m-subtiles 2q,2q+1), MMA2(q) = 16 MFMA
// (2 m-subtiles x 4 n x 2 k), OPEN = s_barrier + lgkmcnt(0) + sched_barrier.
//
// Stage safety: buf[(t+2)%3] was last read during tile t-1 (all 4 phases),
// whose p3 CLOSE precedes tile-t p0 -> region free. Visibility: wave-local
// vmcnt(4) at tile-t p3 retires stage(t+1) (allows only the 4 stage(t+2)
// loads, which are the newest); CLOSE then broadcasts. B-frag loads are
// consumed by this tile's MFMAs (compiler waits), so they are always
// retired before the manual vmcnt counts them. Never vmcnt(0) mid-loop.
// ---------------------------------------------------------------------------
struct GemmBatch {
  const uint16_t* A[3];
  const uint16_t* B[3];
  void* C[3];
};

template <bool OUT_BF16>
__global__ __launch_bounds__(512, 2) void gemm8p(GemmBatch gb,
                                                 const float* __restrict__ bias,
                                                 int M, int N, int K) {
  constexpr int BM = 256, BK = 64;
  __shared__ __align__(16) uint16_t Alds[3][BM * BK];  // 3 x 32 KB

  // XCD-stripe decode: w = xcd + 8*(bn + nbn*(bml + bmpx*z))
  const int w = blockIdx.x;
  const int xcd = w & 7;
  int local = w >> 3;
  const int nbn = N >> 8;
  const int bmpx = (M >> 8) >> 3;
  const int bn = local % nbn;
  local /= nbn;
  const int bml = local % bmpx;
  const int z = local / bmpx;
  const int bm0 = (xcd * bmpx + bml) * BM;
  const int bn0 = bn * 256;

  const uint16_t* __restrict__ Ap = gb.A[z];
  const uint16_t* __restrict__ Bp = gb.B[z];
  void* __restrict__ Cp = gb.C[z];

  const int tid = threadIdx.x;
  const int wave = tid >> 6;
  const int lane = tid & 63;
  const int quad = lane >> 4;
  const int l16 = lane & 15;
  const int wm = (wave >> 2) * 128;  // 2 wave-rows
  const int wn = (wave & 3) * 64;    // 4 wave-cols

  f32x4 acc[8][4];
#pragma unroll
  for (int i = 0; i < 8; ++i)
#pragma unroll
    for (int j = 0; j < 4; ++j) acc[i][j] = (f32x4){0.f, 0.f, 0.f, 0.f};

  // A staging: chunk p = h*1024 + wave*128 + j*64 + lane; m=p>>3, c=p&7,
  // source col-chunk lc = c ^ ((m>>1)&7)  (pre-swizzled source, rule #21).
  size_t aofs[2][2];
  int lofs[2][2];
#pragma unroll
  for (int h = 0; h < 2; ++h)
#pragma unroll
    for (int j = 0; j < 2; ++j) {
      const int p = h * 1024 + wave * 128 + j * 64 + lane;
      const int m = p >> 3;
      const int lc = (p & 7) ^ ((m >> 1) & 7);
      aofs[h][j] = (size_t)(bm0 + m) * K + lc * 8;
      lofs[h][j] = (h * 1024 + wave * 128 + j * 64) * 8;  // wave-uniform
    }

  auto SA = [&](int tile, int h) {
    uint16_t* base = Alds[tile % 3];
#pragma unroll
    for (int j = 0; j < 2; ++j)
      gload_lds16(Ap + aofs[h][j] + (size_t)tile * BK, base + lofs[h][j]);
  };

  // B-frag row bases: Bf[s][k] = B[bn0+wn+s*16+l16][t*64 + k*32 + quad*8 ..+7]
  const uint16_t* Brow[4];
#pragma unroll
  for (int s = 0; s < 4; ++s)
    Brow[s] = Bp + (size_t)(bn0 + wn + s * 16 + l16) * K + quad * 8;

  s16x8 Af[2][2], Bf[4][2];
  auto LDA2 = [&](int buf, int q) {
#pragma unroll
    for (int s = 0; s < 2; ++s) {
      const int ml = wm + (q * 2 + s) * 16 + l16;
      const int sw = (ml >> 1) & 7;
#pragma unroll
      for (int k = 0; k < 2; ++k) {
        const int cc = ml * 8 + ((k * 4 + quad) ^ sw);
        Af[s][k] = *(const s16x8*)&Alds[buf][cc * 8];
      }
    }
  };
  auto OPEN = [&]() {
    __builtin_amdgcn_s_barrier();
    asm volatile("s_waitcnt lgkmcnt(0)" ::: "memory");
    __builtin_amdgcn_sched_barrier(0);
  };
  auto MMA2 = [&](int q) {
    __builtin_amdgcn_s_setprio(1);
#pragma unroll
    for (int s = 0; s < 2; ++s)
#pragma unroll
      for (int n = 0; n < 4; ++n)
#pragma unroll
        for (int k = 0; k < 2; ++k)
          acc[q * 2 + s][n] = __builtin_amdgcn_mfma_f32_16x16x32_bf16(
              Af[s][k], Bf[n][k], acc[q * 2 + s][n], 0, 0, 0);
    __builtin_amdgcn_s_setprio(0);
  };
  auto CLOSE = [&]() { __builtin_amdgcn_s_barrier(); };

  const int NT = K >> 6;  // 16 K-tiles (K=1024); requires NT >= 3

  // prologue: stage tiles 0 and 1 (8 gloads); need tile0 -> allow tile1's 4
  SA(0, 0); SA(0, 1); SA(1, 0); SA(1, 1);
  asm volatile("s_waitcnt vmcnt(4)" ::: "memory");
  __builtin_amdgcn_s_barrier();

  for (int t = 0; t < NT; ++t) {
    const int buf = t % 3;
    const bool more = (t + 2 < NT);  // block-uniform

    // B fragments for this tile -> regs (compiler handles the dep waits)
#pragma unroll
    for (int s = 0; s < 4; ++s)
#pragma unroll
      for (int k = 0; k < 2; ++k)
        Bf[s][k] = *(const s16x8*)(Brow[s] + (size_t)t * BK + k * 32);

    // p0
    LDA2(buf, 0);
    if (more) SA(t + 2, 0);
    OPEN(); MMA2(0); CLOSE();
    // p1
    LDA2(buf, 1);
    if (more) SA(t + 2, 1);
    OPEN(); MMA2(1); CLOSE();
    // p2
    LDA2(buf, 2);
    OPEN(); MMA2(2); CLOSE();
    // p3: counted vmcnt BEFORE the closing barrier
    LDA2(buf, 3);
    OPEN(); MMA2(3);
    if (more) asm volatile("s_waitcnt vmcnt(4)" ::: "memory");
    else      asm volatile("s_waitcnt vmcnt(0)" ::: "memory");
    CLOSE();
  }

  // epilogue: C/D layout col = lane&15, row = quad*4 + r (m89-verified)
#pragma unroll
  for (int sm = 0; sm < 8; ++sm) {
    const int mrow = bm0 + wm + sm * 16 + quad * 4;
#pragma unroll
    for (int sn = 0; sn < 4; ++sn) {
      const int ncol = bn0 + wn + sn * 16 + l16;
      if constexpr (OUT_BF16) {
        uint16_t* Cb = (uint16_t*)Cp;
#pragma unroll
        for (int r = 0; r < 4; ++r) Cb[(size_t)(mrow + r) * N + ncol] = f2bf(acc[sm][sn][r]);
      } else {
        float* Cf = (float*)Cp;
        const float bv = bias[ncol];
#pragma unroll
        for (int r = 0; r < 4; ++r) Cf[(size_t)(mrow + r) * N + ncol] = acc[sm][sn][r] + bv;
      }
    }
  }
}

// ---------------------------------------------------------------------------
// MFMA attention: one WAVE per token. S = Q·K^T via 2x mfma_16x16x32_bf16;
// softmax over g via shfl_xor within 16-lane groups; P through 512B LDS to
// A-layout; V staged coalesced into an XOR-swizzled LDS tile; PV = 4x
// zero-padded mfma_16x16x32.
// R5: plds/vlds are PER-WAVE buffers -> __syncthreads (block barrier +
// implicit vmcnt(0) drain) replaced by wave-local lgkmcnt(0)+sched_barrier.
// Store into "buggy reshape" position X2[b, h*128 + n/16, (n%16)*64 + d].
// ---------------------------------------------------------------------------
__global__ __launch_bounds__(256) void attn_kernel(const uint16_t* __restrict__ qb,
                                                   const uint16_t* __restrict__ kb,
                                                   const uint16_t* __restrict__ vb,
                                                   uint16_t* __restrict__ x2b) {
  __shared__ __align__(16) uint16_t plds[4][16 * 16];  // per-wave P (16x16 bf16)
  __shared__ __align__(16) uint16_t vlds[4][16 * 64];  // per-wave V tile, swizzled

  const int tid = threadIdx.x;
  const int wave = tid >> 6;
  const int lane = tid & 63;
  const int quad = lane >> 4;
  const int l16 = lane & 15;
  const int token = blockIdx.x * 4 + wave;
  const int b = token >> 11;
  const int n = token & 2047;
  const size_t base = (size_t)token * 1024;

  // --- stage V (coalesced 16B chunks, XOR-swizzled columns) ---
  {
    const uint16_t* vt = vb + base;  // 16x64 bf16, contiguous
    uint16_t* vl = vlds[wave];
#pragma unroll
    for (int c2 = 0; c2 < 2; ++c2) {
      const int p = lane + c2 * 64;  // chunk index; src = 16B at p*16
      const int g = p >> 3;
      const int cc = p & 7;
      const int cs = cc ^ (2 * (g >> 3));
      *(uint4*)&vl[g * 64 + cs * 8] = *(const uint4*)&vt[p * 8];
    }
  }

  // --- S = Q K^T (16x16, K=64) ---
  const uint16_t* qrow = qb + base + l16 * 64 + quad * 8;
  const uint16_t* krow = kb + base + l16 * 64 + quad * 8;
  s16x8 aq0 = *(const s16x8*)qrow;
  s16x8 aq1 = *(const s16x8*)(qrow + 32);
  s16x8 bk0 = *(const s16x8*)krow;
  s16x8 bk1 = *(const s16x8*)(krow + 32);
  f32x4 s = (f32x4){0.f, 0.f, 0.f, 0.f};
  s = __builtin_amdgcn_mfma_f32_16x16x32_bf16(aq0, bk0, s, 0, 0, 0);
  s = __builtin_amdgcn_mfma_f32_16x16x32_bf16(aq1, bk1, s, 0, 0, 0);
  // lane holds S[h=quad*4+r][g=l16], r=0..3

  // --- softmax over g (across the 16 lanes sharing quad) ---
  float p[4];
#pragma unroll
  for (int r = 0; r < 4; ++r) {
    float v = s[r] * 0.125f;  // SCALE = 64^-0.5
    float mx = v;
#pragma unroll
    for (int off = 1; off < 16; off <<= 1) mx = fmaxf(mx, __shfl_xor(mx, off));
    float e = __expf(v - mx);
    float sum = e;
#pragma unroll
    for (int off = 1; off < 16; off <<= 1) sum += __shfl_xor(sum, off);
    p[r] = e / sum;
  }

  // --- transpose P to A-layout via LDS (per-wave buffer: wave-local sync) ---
  uint16_t* pb = plds[wave];
#pragma unroll
  for (int r = 0; r < 4; ++r) pb[(quad * 4 + r) * 16 + l16] = f2bf(p[r]);
  asm volatile("s_waitcnt lgkmcnt(0)" ::: "memory");
  __builtin_amdgcn_sched_barrier(0);
  s16x8 ap = (s16x8){0, 0, 0, 0, 0, 0, 0, 0};
  if (quad < 2) ap = *(const s16x8*)&pb[l16 * 16 + quad * 8];  // P[l16][quad*8+j]

  // --- V B-frags from LDS: bv[c][j] = V[g=quad*8+j][d=c*16+l16] ---
  s16x8 bv[4];
#pragma unroll
  for (int c = 0; c < 4; ++c) bv[c] = (s16x8){0, 0, 0, 0, 0, 0, 0, 0};
  if (quad < 2) {
    const uint16_t* vl = vlds[wave];
#pragma unroll
    for (int c = 0; c < 4; ++c) {
      const int cc = c * 2 + (l16 >> 3);
      const int dlo = l16 & 7;
#pragma unroll
      for (int j = 0; j < 8; ++j) {
        const int g = quad * 8 + j;
        const int cs = cc ^ (2 * (g >> 3));
        bv[c][j] = (short)vl[g * 64 + cs * 8 + dlo];
      }
    }
  }

  // --- X = P V (16x64) ---
  f32x4 xacc[4];
#pragma unroll
  for (int c = 0; c < 4; ++c) {
    xacc[c] = (f32x4){0.f, 0.f, 0.f, 0.f};
    xacc[c] = __builtin_amdgcn_mfma_f32_16x16x32_bf16(ap, bv[c], xacc[c], 0, 0, 0);
  }

  // --- store: lane has x[h=quad*4+r][d=c*16+l16] ---
  uint16_t* xout =
      x2b + (size_t)b * (2048 * 1024) + (size_t)(n & 15) * 64 + (size_t)(n >> 4) * 1024;
#pragma unroll
  for (int c = 0; c < 4; ++c) {
    const int d = c * 16 + l16;
#pragma unroll
    for (int r = 0; r < 4; ++r) {
      const int h = quad * 4 + r;
      xout[(size_t)h * 128 * 1024 + d] = f2bf(xacc[c][r]);
    }
  }
}

// ---------------------------------------------------------------------------
extern "C" void kernel_launch(void* const* d_in, const int* in_sizes, int n_in,
                              void* d_out, int out_size, void* d_ws, size_t ws_size,
                              hipStream_t stream) {
  const float* query = (const float*)d_in[0];
  const float* key = (const float*)d_in[1];
  const float* value = (const float*)d_in[2];
  // d_in[3]=xpos, d_in[4]=ypos unused (rope is None)
  const float* Wq = (const float*)d_in[5];
  const float* Wk = (const float*)d_in[6];
  const float* Wv = (const float*)d_in[7];
  const float* Wp = (const float*)d_in[8];
  const float* bp = (const float*)d_in[9];
  float* out = (float*)d_out;

  const int C = 1024;
  const int M = 8 * 2048;  // 16384 tokens
  const size_t MC = (size_t)M * C;
  const size_t CC = (size_t)C * C;

  // workspace layout (bf16 = uint16), 200 MiB total:
  //   qb,kb,vb,x2b (4x32 MiB), wqb..wpb (4x2 MiB), kin,vin (2x32 MiB)
  //   qin ALIASES x2b (x2b dead until attn; qin dead after QKV GEMM).
  uint16_t* ws = (uint16_t*)d_ws;
  uint16_t* qb = ws;
  uint16_t* kb = qb + MC;
  uint16_t* vb = kb + MC;
  uint16_t* x2b = vb + MC;
  uint16_t* wqb = x2b + MC;
  uint16_t* wkb = wqb + CC;
  uint16_t* wvb = wkb + CC;
  uint16_t* wpb = wvb + CC;
  uint16_t* kin = wpb + CC;
  uint16_t* vin = kin + MC;
  uint16_t* qin = x2b;  // alias (see above)

  // convert q/k/v inputs + all 4 weights to bf16 in one launch
  cvt_all_kernel<<<dim3(26624), dim3(256), 0, stream>>>(
      query, key, value, Wq, Wk, Wv, Wp, qin, kin, vin, wqb, wkb, wvb, wpb);

  // batched QKV projections: 256x256 tiles, grid = 64 m * 4 n * 3 = 768
  GemmBatch qkv;
  qkv.A[0] = qin;  qkv.B[0] = wqb;  qkv.C[0] = qb;
  qkv.A[1] = kin;  qkv.B[1] = wkb;  qkv.C[1] = kb;
  qkv.A[2] = vin;  qkv.B[2] = wvb;  qkv.C[2] = vb;
  gemm8p<true><<<dim3((M / 256) * (C / 256) * 3), dim3(512), 0, stream>>>(qkv, nullptr,
                                                                          M, C, C);

  attn_kernel<<<dim3(M / 4), dim3(256), 0, stream>>>(qb, kb, vb, x2b);

  GemmBatch fin;
  fin.A[0] = x2b;  fin.B[0] = wpb;  fin.C[0] = out;
  fin.A[1] = x2b;  fin.B[1] = wpb;  fin.C[1] = out;
  fin.A[2] = x2b;  fin.B[2] = wpb;  fin.C[2] = out;
  gemm8p<false><<<dim3((M / 256) * (C / 256)), dim3(512), 0, stream>>>(fin, bp, M, C, C);
}